// Round 1
// baseline (231.532 us; speedup 1.0000x reference)
//
#include <hip/hip_runtime.h>

// Problem constants (match reference)
constexpr int B    = 64;
constexpr int E    = 512;
constexpr int P    = 31;    // patch size
constexpr int S    = 200;   // canvas size
constexpr int HALF = 15;

// Tiling
constexpr int BAND    = 25;           // rows per canvas band (S % BAND == 0)
constexpr int NBANDS  = S / BAND;     // 8
constexpr int THREADS = 512;          // 8 waves
constexpr int NWAVES  = THREADS / 64;

__global__ __launch_bounds__(THREADS)
void imgs4dto3d_scatter_kernel(const float* __restrict__ img,
                               const int*   __restrict__ xyz,
                               float*       __restrict__ out)
{
    const int blk    = blockIdx.x;
    const int b      = blk >> 3;        // batch
    const int band   = blk & (NBANDS - 1);
    const int band_r0 = band * BAND;

    __shared__ float canvas[BAND * S];  // 25*200*4 = 20 KB

    const int tid = threadIdx.x;
    // zero the band
    for (int i = tid; i < BAND * S; i += THREADS) canvas[i] = 0.0f;
    __syncthreads();

    const int wid  = tid >> 6;
    const int lane = tid & 63;

    // each wave handles a strided subset of emitters
    for (int e = wid; e < E; e += NWAVES) {
        const int base3 = (b * E + e) * 3;
        const int x = xyz[base3 + 0];   // row center
        const int y = xyz[base3 + 1];   // col center

        // intersect patch rows [x-15, x+16) with band rows [band_r0, band_r0+BAND)
        const int r_lo = max(x - HALF, band_r0);
        const int r_hi = min(x + HALF + 1, band_r0 + BAND);
        if (r_lo >= r_hi) continue;

        const int i_lo  = r_lo - (x - HALF);       // first patch row in band
        const int nrows = r_hi - r_lo;
        const int npix  = nrows * P;

        const float* src = img + ((size_t)(b * E + e) * (P * P)) + (size_t)i_lo * P;
        const int c0      = y - HALF;              // leftmost canvas col (>= 0)
        const int ldsrow0 = r_lo - band_r0;

        for (int q = lane; q < npix; q += 64) {
            const int i = q / P;          // row within the in-band slice
            const int j = q - i * P;      // col within patch
            const float v = src[q];       // contiguous -> coalesced
            atomicAdd(&canvas[(ldsrow0 + i) * S + (c0 + j)], v);
        }
    }
    __syncthreads();

    // write the band out with plain coalesced float4 stores
    float4* outv = reinterpret_cast<float4*>(out + (size_t)b * (S * S) + (size_t)band_r0 * S);
    const float4* cv = reinterpret_cast<const float4*>(canvas);
    constexpr int NV4 = (BAND * S) / 4;   // 1250, exact
    for (int i = tid; i < NV4; i += THREADS) {
        outv[i] = cv[i];
    }
}

extern "C" void kernel_launch(void* const* d_in, const int* in_sizes, int n_in,
                              void* d_out, int out_size, void* d_ws, size_t ws_size,
                              hipStream_t stream)
{
    const float* img = (const float*)d_in[0];   // [B, E, P, P] fp32
    const int*   xyz = (const int*)d_in[1];     // [B, E, 3] int32
    float*       out = (float*)d_out;           // [B, 1, S, S] fp32

    imgs4dto3d_scatter_kernel<<<B * NBANDS, THREADS, 0, stream>>>(img, xyz, out);
}

// Round 2
// 180.118 us; speedup vs baseline: 1.2855x; 1.2855x over previous
//
#include <hip/hip_runtime.h>

// Problem constants (match reference)
constexpr int B    = 64;
constexpr int E    = 512;
constexpr int P    = 31;    // patch size
constexpr int S    = 200;   // canvas size
constexpr int HALF = 15;

// Tiling
constexpr int BAND    = 10;           // rows per canvas band (S % BAND == 0)
constexpr int NBANDS  = S / BAND;     // 20
constexpr int THREADS = 256;          // 4 waves
constexpr int NWAVES  = THREADS / 64;

__global__ __launch_bounds__(THREADS)
void imgs4dto3d_scatter_kernel(const float* __restrict__ img,
                               const int*   __restrict__ xyz,
                               float*       __restrict__ out)
{
    const int blk     = blockIdx.x;
    const int b       = blk / NBANDS;
    const int band    = blk % NBANDS;
    const int band_r0 = band * BAND;

    __shared__ __align__(16) float canvas[BAND * S];   // 8 KB
    __shared__ unsigned int list[E];                   // 2 KB (worst case all intersect)
    __shared__ int cnt;

    const int tid = threadIdx.x;
    if (tid == 0) cnt = 0;

    // zero the band (vectorized)
    {
        float4* cz = reinterpret_cast<float4*>(canvas);
        constexpr int NZ = (BAND * S) / 4;  // 500
        for (int i = tid; i < NZ; i += THREADS) cz[i] = make_float4(0.f, 0.f, 0.f, 0.f);
    }
    __syncthreads();

    // ---- Phase 1: compact intersecting emitters into LDS ----
    // pack: e[0:8] | i_lo[9:13] | lrow[14:17] | nrows[18:21] | c0[22:29]
    for (int e = tid; e < E; e += THREADS) {
        const int base3 = (b * E + e) * 3;
        const int x = xyz[base3 + 0];   // row center
        const int y = xyz[base3 + 1];   // col center
        const int r_lo = max(x - HALF, band_r0);
        const int r_hi = min(x + HALF + 1, band_r0 + BAND);
        if (r_lo < r_hi) {
            const unsigned int i_lo  = (unsigned)(r_lo - (x - HALF));   // 0..30
            const unsigned int lrow  = (unsigned)(r_lo - band_r0);      // 0..9
            const unsigned int nrows = (unsigned)(r_hi - r_lo);         // 1..10
            const unsigned int c0    = (unsigned)(y - HALF);            // 0..169
            const unsigned int packed =
                (unsigned)e | (i_lo << 9) | (lrow << 14) | (nrows << 18) | (c0 << 22);
            const int pos = atomicAdd(&cnt, 1);
            list[pos] = packed;
        }
    }
    __syncthreads();

    // ---- Phase 2: scatter patch pixels into the LDS band ----
    const int wid  = tid >> 6;
    const int lane = tid & 63;
    const int n    = cnt;

    const int  half   = lane >> 5;        // 0 or 1 (row pair)
    const int  col    = lane & 31;        // 0..31
    const bool colact = (col < P);        // lane 31/63 idle

    for (int idx = wid; idx < n; idx += NWAVES) {
        const unsigned int pk = list[idx];
        const int e     = (int)(pk & 511u);
        const int i_lo  = (int)((pk >> 9)  & 31u);
        const int lrow  = (int)((pk >> 14) & 15u);
        const int nrows = (int)((pk >> 18) & 15u);
        const int c0    = (int)(pk >> 22);

        const float* src = img + (size_t)(b * E + e) * (P * P) + (size_t)i_lo * P;

        // issue all loads first (up to 5 in flight), then the LDS atomics
        float v[5];
        bool  act[5];
        #pragma unroll
        for (int k = 0; k < 5; ++k) {
            const int r = 2 * k + half;
            act[k] = colact && (r < nrows);
            v[k]   = act[k] ? src[r * P + col] : 0.0f;
        }
        #pragma unroll
        for (int k = 0; k < 5; ++k) {
            const int r = 2 * k + half;
            if (act[k]) atomicAdd(&canvas[(lrow + r) * S + (c0 + col)], v[k]);
        }
    }
    __syncthreads();

    // ---- Phase 3: write the band out (each output pixel written exactly once) ----
    float4* outv = reinterpret_cast<float4*>(out + (size_t)b * (S * S) + (size_t)band_r0 * S);
    const float4* cv = reinterpret_cast<const float4*>(canvas);
    constexpr int NV4 = (BAND * S) / 4;   // 500
    for (int i = tid; i < NV4; i += THREADS) {
        outv[i] = cv[i];
    }
}

extern "C" void kernel_launch(void* const* d_in, const int* in_sizes, int n_in,
                              void* d_out, int out_size, void* d_ws, size_t ws_size,
                              hipStream_t stream)
{
    const float* img = (const float*)d_in[0];   // [B, E, P, P] fp32
    const int*   xyz = (const int*)d_in[1];     // [B, E, 3] int32
    float*       out = (float*)d_out;           // [B, 1, S, S] fp32

    imgs4dto3d_scatter_kernel<<<B * NBANDS, THREADS, 0, stream>>>(img, xyz, out);
}